// Round 4
// baseline (266.654 us; speedup 1.0000x reference)
//
#include <hip/hip_runtime.h>
#include <stdint.h>

typedef int v4i __attribute__((ext_vector_type(4)));
typedef int v16i __attribute__((ext_vector_type(16)));

#define GLOBAL_AS __attribute__((address_space(1)))
#define LDS_AS __attribute__((address_space(3)))

// Exact replication of reference rounding:
// q = clamp(rint(x / s + z), 0, 255); store (q - zi) as int8.
__device__ __forceinline__ int quant1(float x, float s, float z, int zi) {
    float q = rintf(x / s + z);          // IEEE division + round-half-even, matches np
    q = fminf(fmaxf(q, 0.0f), 255.0f);
    return (int)q - zi;
}

__device__ __forceinline__ unsigned qpack4(float4 v, float s, float z, int zi) {
    unsigned q0 = (unsigned)(quant1(v.x, s, z, zi) & 255);
    unsigned q1 = (unsigned)(quant1(v.y, s, z, zi) & 255);
    unsigned q2 = (unsigned)(quant1(v.z, s, z, zi) & 255);
    unsigned q3 = (unsigned)(quant1(v.w, s, z, zi) & 255);
    return q0 | (q1 << 8) | (q2 << 16) | (q3 << 24);
}

// ---------------- quantize x1 (elementwise, keeps layout [*, K]) ----------------
__global__ __launch_bounds__(256) void quant_lin(const float* __restrict__ x,
                                                 int8_t* __restrict__ out,
                                                 const float* __restrict__ sp,
                                                 const float* __restrict__ zp,
                                                 long n16) {
    float s = sp[0], z = zp[0];
    int zi = (int)rintf(z);
    long i = (long)blockIdx.x * 256 + threadIdx.x;
    if (i >= n16) return;
    const float4* xv = (const float4*)x;
    uint4 w;
    w.x = qpack4(xv[i * 4 + 0], s, z, zi);
    w.y = qpack4(xv[i * 4 + 1], s, z, zi);
    w.z = qpack4(xv[i * 4 + 2], s, z, zi);
    w.w = qpack4(xv[i * 4 + 3], s, z, zi);
    ((uint4*)out)[i] = w;
}

// ------------- quantize x2 [K][N] -> int8 transposed [N][K] -------------
__global__ __launch_bounds__(256) void quant_bt(const float* __restrict__ x,
                                                int8_t* __restrict__ out,
                                                const float* __restrict__ sp,
                                                const float* __restrict__ zp) {
    constexpr int K = 4096, N = 4096;
    float s = sp[0], z = zp[0];
    int zi = (int)rintf(z);
    size_t bin = (size_t)blockIdx.z * K * N;
    int tid = threadIdx.x;
    int bk = tid >> 4;   // 0..15: k-block of 4 rows
    int bn = tid & 15;   // 0..15: n-block of 4 cols
    int k0 = blockIdx.y * 64, n0 = blockIdx.x * 64;
    __shared__ unsigned lds[64][17];
    unsigned o0 = 0, o1 = 0, o2 = 0, o3 = 0;
#pragma unroll
    for (int r = 0; r < 4; ++r) {
        float4 v = *(const float4*)(x + bin + (size_t)(k0 + bk * 4 + r) * N + n0 + bn * 4);
        o0 |= (unsigned)(quant1(v.x, s, z, zi) & 255) << (r * 8);
        o1 |= (unsigned)(quant1(v.y, s, z, zi) & 255) << (r * 8);
        o2 |= (unsigned)(quant1(v.z, s, z, zi) & 255) << (r * 8);
        o3 |= (unsigned)(quant1(v.w, s, z, zi) & 255) << (r * 8);
    }
    lds[bn * 4 + 0][bk] = o0;
    lds[bn * 4 + 1][bk] = o1;
    lds[bn * 4 + 2][bk] = o2;
    lds[bn * 4 + 3][bk] = o3;
    __syncthreads();
    int nl = tid >> 2, ch = tid & 3;
    uint4 w;
    w.x = lds[nl][ch * 4 + 0];
    w.y = lds[nl][ch * 4 + 1];
    w.z = lds[nl][ch * 4 + 2];
    w.w = lds[nl][ch * 4 + 3];
    *(uint4*)(out + bin + (size_t)(n0 + nl) * K + k0 + ch * 16) = w;
}

// ------------- int8 GEMM, 256x256 tile, 8-phase schedule, 32x32x32 MFMA -------------
// C[b] = Aq[b](MxK) * BqT[b](NxK)^T, mfma_i32_32x32x32_i8 (4404 TOPS ceiling,
// 2x ops per LDS byte vs 16x16x64). 512 threads = 8 waves (2Mx4N), per-wave
// 128x64 output = 4x2 tiles of 32x32, BK=128.
// LDS 128 KiB: [buf][mat][khalf] regions of 256 rows x 64 B, chunk-XOR swizzle
// (c ^ ((row>>1)&3)) via pre-swizzled global source (linear LDS dest).
// Counted vmcnt(4) once per K-half pair (phases 2 & 4) - never 0 in the loop.
__global__ __launch_bounds__(512, 2) void gemm_i8(const int8_t* __restrict__ A,
                                                  const int8_t* __restrict__ Bt,
                                                  float* __restrict__ C,
                                                  const float* __restrict__ sp1,
                                                  const float* __restrict__ sp2) {
    constexpr int M = 2048, N = 4096, K = 4096;
    constexpr int BM = 256, BN = 256, BK = 128;
    constexpr int NT = K / BK;   // 32
    constexpr int NBN = N / BN;  // 16

    extern __shared__ char smem[];

    int b = blockIdx.z;
    const int8_t* Ab = A + (size_t)b * M * K;
    const int8_t* Bb = Bt + (size_t)b * N * K;
    float* Cb = C + (size_t)b * M * N;

    // XCD-aware swizzle; grid.x = 128, divisible by 8 -> bijective
    int nwg = gridDim.x;
    int wg = blockIdx.x;
    wg = (wg & 7) * (nwg >> 3) + (wg >> 3);
    int by = wg / NBN, bx = wg % NBN;
    int m0 = by * BM, n0 = bx * BN;

    int tid = threadIdx.x;
    int lane = tid & 63, wid = tid >> 6;
    int wr = wid >> 2, wc = wid & 3;  // 2 x 4 waves
    int l31 = lane & 31, hi = lane >> 5;

    const int8_t* Abase = Ab + (size_t)m0 * K;
    const int8_t* Bbase = Bb + (size_t)n0 * K;

    // ---- persistent per-thread staging pointers (advance by BK per tile) ----
    int row0 = tid >> 2, cc0 = tid & 3;
    int sw0 = cc0 ^ ((row0 >> 1) & 3);
    const size_t JSTEP = (size_t)128 * K;  // j=1 load is exactly +128 rows
    const int8_t* pA0 = Abase + (size_t)row0 * K + sw0 * 16;  // kh=0
    const int8_t* pA1 = pA0 + 64;                             // kh=1
    const int8_t* pB0 = Bbase + (size_t)row0 * K + sw0 * 16;
    const int8_t* pB1 = pB0 + 64;
    const unsigned dbase = (unsigned)tid * 16;

    // per-lane swizzled byte offsets within a (mat,kh) region for ds_read_b128
    // fragment: row = tile*32 + l31, chunk = j*2 + hi (j = kstep within K-half)
    int aoff[4][2], boff[2][2];
#pragma unroll
    for (int m = 0; m < 4; ++m) {
        int r = wr * 128 + m * 32 + l31;
#pragma unroll
        for (int j = 0; j < 2; ++j)
            aoff[m][j] = r * 64 + (((j * 2 + hi) ^ ((r >> 1) & 3)) * 16);
    }
#pragma unroll
    for (int n = 0; n < 2; ++n) {
        int r = wc * 64 + n * 32 + l31;
#pragma unroll
        for (int j = 0; j < 2; ++j)
            boff[n][j] = r * 64 + (((j * 2 + hi) ^ ((r >> 1) & 3)) * 16);
    }

    v16i acc[4][2];
#pragma unroll
    for (int m = 0; m < 4; ++m)
#pragma unroll
        for (int n = 0; n < 2; ++n)
#pragma unroll
            for (int e = 0; e < 16; ++e) acc[m][n][e] = 0;

// stage one K-half of one matrix into buffer `buf` (2 x global_load_lds, 16 KB)
#define ISSUE(p, mat, kh, buf)                                                         \
    {                                                                                  \
        char* dst = smem + ((((buf)*2 + (mat)) * 2 + (kh)) * 16384) + dbase;           \
        __builtin_amdgcn_global_load_lds((const GLOBAL_AS void*)(p),                   \
                                         (LDS_AS void*)dst, 16, 0, 0);                 \
        __builtin_amdgcn_global_load_lds((const GLOBAL_AS void*)((p) + JSTEP),         \
                                         (LDS_AS void*)(dst + 8192), 16, 0, 0);        \
    }

#define MFMA8(mh)                                                                      \
    {                                                                                  \
        __builtin_amdgcn_s_setprio(1);                                                 \
        _Pragma("unroll") for (int m = 0; m < 2; ++m)                                  \
            _Pragma("unroll") for (int n = 0; n < 2; ++n)                              \
                _Pragma("unroll") for (int j = 0; j < 2; ++j)                          \
                    acc[(mh)*2 + m][n] = __builtin_amdgcn_mfma_i32_32x32x32_i8(        \
                        af[m][j], bf[n][j], acc[(mh)*2 + m][n], 0, 0, 0);              \
        __builtin_amdgcn_s_setprio(0);                                                 \
    }

#define BAR_PRE()                                                                      \
    __builtin_amdgcn_s_barrier();                                                      \
    asm volatile("s_waitcnt lgkmcnt(0)" ::: "memory");                                 \
    __builtin_amdgcn_sched_barrier(0);

    // prologue: stage tile 0 into buf 0; retire kh=0 regions before phase 1
    ISSUE(pA0, 0, 0, 0);
    ISSUE(pB0, 1, 0, 0);
    ISSUE(pA1, 0, 1, 0);
    ISSUE(pB1, 1, 1, 0);
    asm volatile("s_waitcnt vmcnt(4)" ::: "memory");
    __builtin_amdgcn_s_barrier();

    for (int jt = 0; jt < NT; ++jt) {
        int buf = jt & 1;
        const char* Ar0 = smem + (buf * 4 + 0) * 16384;
        const char* Ar1 = smem + (buf * 4 + 1) * 16384;
        const char* Br0 = smem + (buf * 4 + 2) * 16384;
        const char* Br1 = smem + (buf * 4 + 3) * 16384;
        bool pf = (jt + 1 < NT);
        pA0 += BK; pA1 += BK; pB0 += BK; pB1 += BK;

        v4i af[2][2], bf[2][2];
        // ---- phase 1: kh=0, M-tiles 0,1 (also loads B for whole K-half) ----
#pragma unroll
        for (int n = 0; n < 2; ++n)
#pragma unroll
            for (int j = 0; j < 2; ++j) bf[n][j] = *(const v4i*)(Br0 + boff[n][j]);
#pragma unroll
        for (int m = 0; m < 2; ++m)
#pragma unroll
            for (int j = 0; j < 2; ++j) af[m][j] = *(const v4i*)(Ar0 + aoff[m][j]);
        if (pf) ISSUE(pA0, 0, 0, buf ^ 1);
        BAR_PRE();
        MFMA8(0);
        __builtin_amdgcn_s_barrier();

        // ---- phase 2: kh=0, M-tiles 2,3 (B reused) ----
#pragma unroll
        for (int m = 0; m < 2; ++m)
#pragma unroll
            for (int j = 0; j < 2; ++j) af[m][j] = *(const v4i*)(Ar0 + aoff[2 + m][j]);
        if (pf) ISSUE(pB0, 1, 0, buf ^ 1);
        BAR_PRE();
        MFMA8(1);
        if (pf) asm volatile("s_waitcnt vmcnt(4)" ::: "memory");
        else    asm volatile("s_waitcnt vmcnt(0)" ::: "memory");
        __builtin_amdgcn_s_barrier();

        // ---- phase 3: kh=1, M-tiles 0,1 ----
#pragma unroll
        for (int n = 0; n < 2; ++n)
#pragma unroll
            for (int j = 0; j < 2; ++j) bf[n][j] = *(const v4i*)(Br1 + boff[n][j]);
#pragma unroll
        for (int m = 0; m < 2; ++m)
#pragma unroll
            for (int j = 0; j < 2; ++j) af[m][j] = *(const v4i*)(Ar1 + aoff[m][j]);
        if (pf) ISSUE(pA1, 0, 1, buf ^ 1);
        BAR_PRE();
        MFMA8(0);
        __builtin_amdgcn_s_barrier();

        // ---- phase 4: kh=1, M-tiles 2,3 ----
#pragma unroll
        for (int m = 0; m < 2; ++m)
#pragma unroll
            for (int j = 0; j < 2; ++j) af[m][j] = *(const v4i*)(Ar1 + aoff[2 + m][j]);
        if (pf) ISSUE(pB1, 1, 1, buf ^ 1);
        BAR_PRE();
        MFMA8(1);
        if (pf) asm volatile("s_waitcnt vmcnt(4)" ::: "memory");
        __builtin_amdgcn_s_barrier();
    }

    // epilogue: C/D map for 32x32: col = l31, row = (reg&3) + 8*(reg>>2) + 4*hi
    float sc = sp1[0] * sp2[0];
#pragma unroll
    for (int mt = 0; mt < 4; ++mt) {
#pragma unroll
        for (int n = 0; n < 2; ++n) {
            float* pc = Cb + (size_t)(m0 + wr * 128 + mt * 32 + 4 * hi) * N +
                        (n0 + wc * 64 + n * 32 + l31);
#pragma unroll
            for (int g = 0; g < 4; ++g)
#pragma unroll
                for (int r = 0; r < 4; ++r)
                    pc[(size_t)(g * 8 + r) * N] = sc * (float)acc[mt][n][g * 4 + r];
        }
    }
#undef ISSUE
#undef MFMA8
#undef BAR_PRE
}

extern "C" void kernel_launch(void* const* d_in, const int* in_sizes, int n_in,
                              void* d_out, int out_size, void* d_ws, size_t ws_size,
                              hipStream_t stream) {
    const float* x1 = (const float*)d_in[0];
    const float* x2 = (const float*)d_in[1];
    const float* s1 = (const float*)d_in[2];
    const float* z1 = (const float*)d_in[3];
    const float* s2 = (const float*)d_in[4];
    const float* z2 = (const float*)d_in[5];
    float* out = (float*)d_out;

    const int B = 4, M = 2048, K = 4096, N = 4096;
    const size_t ASZ = (size_t)B * M * K;   // int8 bytes for all of x1
    const size_t BSZ = (size_t)B * K * N;   // int8 bytes for all of x2
    dim3 blk(256);

    static int lds_attr_set = 0;
    if (!lds_attr_set) {
        (void)hipFuncSetAttribute((const void*)gemm_i8,
                                  hipFuncAttributeMaxDynamicSharedMemorySize, 131072);
        lds_attr_set = 1;
    }

    if (ws_size >= ASZ + BSZ) {
        int8_t* Aq = (int8_t*)d_ws;
        int8_t* Bq = Aq + ASZ;
        long n16 = (long)(ASZ / 16);
        quant_lin<<<dim3((unsigned)(n16 / 256)), blk, 0, stream>>>(x1, Aq, s1, z1, n16);
        quant_bt<<<dim3(N / 64, K / 64, B), blk, 0, stream>>>(x2, Bq, s2, z2);
        gemm_i8<<<dim3((M / 256) * (N / 256), 1, B), dim3(512), 131072, stream>>>(
            Aq, Bq, out, s1, s2);
    } else {
        const size_t AB = (size_t)M * K, BB = (size_t)K * N;
        int8_t* Aq = (int8_t*)d_ws;
        int8_t* Bq = Aq + AB;
        for (int b = 0; b < B; ++b) {
            long n16 = (long)(AB / 16);
            quant_lin<<<dim3((unsigned)(n16 / 256)), blk, 0, stream>>>(x1 + (size_t)b * AB, Aq, s1, z1, n16);
            quant_bt<<<dim3(N / 64, K / 64, 1), blk, 0, stream>>>(x2 + (size_t)b * BB, Bq, s2, z2);
            gemm_i8<<<dim3((M / 256) * (N / 256), 1, 1), dim3(512), 131072, stream>>>(
                Aq, Bq, out + (size_t)b * M * N, s1, s2);
        }
    }
}

// Round 5
// 251.496 us; speedup vs baseline: 1.0603x; 1.0603x over previous
//
#include <hip/hip_runtime.h>
#include <stdint.h>

typedef int v4i __attribute__((ext_vector_type(4)));

#define GLOBAL_AS __attribute__((address_space(1)))
#define LDS_AS __attribute__((address_space(3)))

// Exact replication of reference rounding:
// q = clamp(rint(x / s + z), 0, 255); store (q - zi) as int8.
__device__ __forceinline__ int quant1(float x, float s, float z, int zi) {
    float q = rintf(x / s + z);          // IEEE division + round-half-even, matches np
    q = fminf(fmaxf(q, 0.0f), 255.0f);
    return (int)q - zi;
}

__device__ __forceinline__ unsigned qpack4(float4 v, float s, float z, int zi) {
    unsigned q0 = (unsigned)(quant1(v.x, s, z, zi) & 255);
    unsigned q1 = (unsigned)(quant1(v.y, s, z, zi) & 255);
    unsigned q2 = (unsigned)(quant1(v.z, s, z, zi) & 255);
    unsigned q3 = (unsigned)(quant1(v.w, s, z, zi) & 255);
    return q0 | (q1 << 8) | (q2 << 16) | (q3 << 24);
}

// ---------------- quantize x1 (elementwise, keeps layout [*, K]) ----------------
__global__ __launch_bounds__(256) void quant_lin(const float* __restrict__ x,
                                                 int8_t* __restrict__ out,
                                                 const float* __restrict__ sp,
                                                 const float* __restrict__ zp,
                                                 long n16) {
    float s = sp[0], z = zp[0];
    int zi = (int)rintf(z);
    long i = (long)blockIdx.x * 256 + threadIdx.x;
    if (i >= n16) return;
    const float4* xv = (const float4*)x;
    uint4 w;
    w.x = qpack4(xv[i * 4 + 0], s, z, zi);
    w.y = qpack4(xv[i * 4 + 1], s, z, zi);
    w.z = qpack4(xv[i * 4 + 2], s, z, zi);
    w.w = qpack4(xv[i * 4 + 3], s, z, zi);
    ((uint4*)out)[i] = w;
}

// ------------- quantize x2 [K][N] -> int8 transposed [N][K] -------------
__global__ __launch_bounds__(256) void quant_bt(const float* __restrict__ x,
                                                int8_t* __restrict__ out,
                                                const float* __restrict__ sp,
                                                const float* __restrict__ zp) {
    constexpr int K = 4096, N = 4096;
    float s = sp[0], z = zp[0];
    int zi = (int)rintf(z);
    size_t bin = (size_t)blockIdx.z * K * N;
    int tid = threadIdx.x;
    int bk = tid >> 4;   // 0..15: k-block of 4 rows
    int bn = tid & 15;   // 0..15: n-block of 4 cols
    int k0 = blockIdx.y * 64, n0 = blockIdx.x * 64;
    __shared__ unsigned lds[64][17];
    unsigned o0 = 0, o1 = 0, o2 = 0, o3 = 0;
#pragma unroll
    for (int r = 0; r < 4; ++r) {
        float4 v = *(const float4*)(x + bin + (size_t)(k0 + bk * 4 + r) * N + n0 + bn * 4);
        o0 |= (unsigned)(quant1(v.x, s, z, zi) & 255) << (r * 8);
        o1 |= (unsigned)(quant1(v.y, s, z, zi) & 255) << (r * 8);
        o2 |= (unsigned)(quant1(v.z, s, z, zi) & 255) << (r * 8);
        o3 |= (unsigned)(quant1(v.w, s, z, zi) & 255) << (r * 8);
    }
    lds[bn * 4 + 0][bk] = o0;
    lds[bn * 4 + 1][bk] = o1;
    lds[bn * 4 + 2][bk] = o2;
    lds[bn * 4 + 3][bk] = o3;
    __syncthreads();
    int nl = tid >> 2, ch = tid & 3;
    uint4 w;
    w.x = lds[nl][ch * 4 + 0];
    w.y = lds[nl][ch * 4 + 1];
    w.z = lds[nl][ch * 4 + 2];
    w.w = lds[nl][ch * 4 + 3];
    *(uint4*)(out + bin + (size_t)(n0 + nl) * K + k0 + ch * 16) = w;
}

// ------- int8 GEMM, 256x256 tile, 2-halves-per-tile, counted vmcnt(4) -------
// C[b] = Aq[b](MxK) * BqT[b](NxK)^T, mfma_i32_16x16x64_i8 (0-conflict layout).
// 512 threads = 8 waves (2Mx4N), per-wave 128x64, BK=128 split into 2 K-halves.
// Per half: 12 ds_read_b128 + 4 global_load_lds + 32 MFMA, compiler-scheduled
// (counted lgkmcnt interleave); ONE {lgkmcnt(0); vmcnt(4); s_barrier} per half.
// vmcnt ledger (4 loads issued per half, in-order retire): at each half-end,
// outstanding = 8; vmcnt(4) retires exactly the half staged one period ago,
// which is the data the NEXT half reads. Stages get a full half (~1500 cyc)
// of in-flight time -> HBM latency covered; never drained to 0 in the loop.
__global__ __launch_bounds__(512, 2) void gemm_i8(const int8_t* __restrict__ A,
                                                  const int8_t* __restrict__ Bt,
                                                  float* __restrict__ C,
                                                  const float* __restrict__ sp1,
                                                  const float* __restrict__ sp2) {
    constexpr int M = 2048, N = 4096, K = 4096;
    constexpr int BM = 256, BN = 256, BK = 128;
    constexpr int NT = K / BK;   // 32
    constexpr int NBN = N / BN;  // 16

    extern __shared__ char smem[];

    int b = blockIdx.z;
    const int8_t* Ab = A + (size_t)b * M * K;
    const int8_t* Bb = Bt + (size_t)b * N * K;
    float* Cb = C + (size_t)b * M * N;

    // XCD-aware swizzle; grid.x = 128, divisible by 8 -> bijective
    int nwg = gridDim.x;
    int wg = blockIdx.x;
    wg = (wg & 7) * (nwg >> 3) + (wg >> 3);
    int by = wg / NBN, bx = wg % NBN;
    int m0 = by * BM, n0 = bx * BN;

    int tid = threadIdx.x;
    int lane = tid & 63, wid = tid >> 6;
    int wr = wid >> 2, wc = wid & 3;  // 2 x 4 waves
    int l15 = lane & 15, cb = lane >> 4;

    const int8_t* Abase = Ab + (size_t)m0 * K;
    const int8_t* Bbase = Bb + (size_t)n0 * K;

    // ---- persistent per-thread staging pointers (advance by BK per tile) ----
    int row0 = tid >> 2, cc0 = tid & 3;
    int sw0 = cc0 ^ ((row0 >> 1) & 3);
    const size_t JSTEP = (size_t)128 * K;  // second load is exactly +128 rows
    const int8_t* pA0 = Abase + (size_t)row0 * K + sw0 * 16;  // kh=0
    const int8_t* pA1 = pA0 + 64;                             // kh=1
    const int8_t* pB0 = Bbase + (size_t)row0 * K + sw0 * 16;
    const int8_t* pB1 = pB0 + 64;
    const unsigned dbase = (unsigned)tid * 16;

    // per-lane swizzled within-region byte offsets for fragment ds_reads
    int aoff[8], boff[4];
#pragma unroll
    for (int m = 0; m < 8; ++m) {
        int r = wr * 128 + m * 16 + l15;
        aoff[m] = r * 64 + ((cb ^ ((r >> 1) & 3)) * 16);
    }
#pragma unroll
    for (int n = 0; n < 4; ++n) {
        int r = wc * 64 + n * 16 + l15;
        boff[n] = r * 64 + ((cb ^ ((r >> 1) & 3)) * 16);
    }

    v4i zero = {0, 0, 0, 0};
    v4i acc[8][4];
#pragma unroll
    for (int m = 0; m < 8; ++m)
#pragma unroll
        for (int n = 0; n < 4; ++n) acc[m][n] = zero;

// stage one K-half of one matrix into buffer `buf` (2 x global_load_lds, 16 KB)
#define ISSUE(p, mat, kh, buf)                                                         \
    {                                                                                  \
        char* dst = smem + ((((buf)*2 + (mat)) * 2 + (kh)) * 16384) + dbase;           \
        __builtin_amdgcn_global_load_lds((const GLOBAL_AS void*)(p),                   \
                                         (LDS_AS void*)dst, 16, 0, 0);                 \
        __builtin_amdgcn_global_load_lds((const GLOBAL_AS void*)((p) + JSTEP),         \
                                         (LDS_AS void*)(dst + 8192), 16, 0, 0);        \
    }

// one K-half: 12 reads + optional stage-issue + 32 MFMA (compiler-interleaved)
#define HALF(Ar, Br, DOISSUE, NWAIT)                                                   \
    {                                                                                  \
        v4i af[8], bf[4];                                                              \
        _Pragma("unroll") for (int n = 0; n < 4; ++n)                                  \
            bf[n] = *(const v4i*)((Br) + boff[n]);                                     \
        _Pragma("unroll") for (int m = 0; m < 8; ++m)                                  \
            af[m] = *(const v4i*)((Ar) + aoff[m]);                                     \
        DOISSUE;                                                                       \
        __builtin_amdgcn_s_setprio(1);                                                 \
        _Pragma("unroll") for (int m = 0; m < 8; ++m)                                  \
            _Pragma("unroll") for (int n = 0; n < 4; ++n)                              \
                acc[m][n] = __builtin_amdgcn_mfma_i32_16x16x64_i8(af[m], bf[n],        \
                                                                  acc[m][n], 0, 0, 0); \
        __builtin_amdgcn_s_setprio(0);                                                 \
        asm volatile("s_waitcnt lgkmcnt(0)\n\ts_waitcnt vmcnt(" #NWAIT ")" ::: "memory"); \
        __builtin_amdgcn_s_barrier();                                                  \
        asm volatile("" ::: "memory");                                                 \
    }

    // prologue: stage tile 0 (8 loads, kh0 first); retire kh0 before loop
    ISSUE(pA0, 0, 0, 0);
    ISSUE(pB0, 1, 0, 0);
    ISSUE(pA1, 0, 1, 0);
    ISSUE(pB1, 1, 1, 0);
    asm volatile("s_waitcnt vmcnt(4)" ::: "memory");
    __builtin_amdgcn_s_barrier();
    asm volatile("" ::: "memory");

    for (int jt = 0; jt < NT - 1; ++jt) {
        int buf = jt & 1;
        const char* Ar0 = smem + (buf * 4 + 0) * 16384;
        const char* Ar1 = smem + (buf * 4 + 1) * 16384;
        const char* Br0 = smem + (buf * 4 + 2) * 16384;
        const char* Br1 = smem + (buf * 4 + 3) * 16384;
        pA0 += BK; pA1 += BK; pB0 += BK; pB1 += BK;

        HALF(Ar0, Br0, ISSUE(pA0, 0, 0, buf ^ 1); ISSUE(pB0, 1, 0, buf ^ 1), 4)
        HALF(Ar1, Br1, ISSUE(pA1, 0, 1, buf ^ 1); ISSUE(pB1, 1, 1, buf ^ 1), 4)
    }
    {   // last tile: no prefetch; drain remaining loads before each half's reads
        int buf = (NT - 1) & 1;
        const char* Ar0 = smem + (buf * 4 + 0) * 16384;
        const char* Ar1 = smem + (buf * 4 + 1) * 16384;
        const char* Br0 = smem + (buf * 4 + 2) * 16384;
        const char* Br1 = smem + (buf * 4 + 3) * 16384;
        HALF(Ar0, Br0, , 0)
        HALF(Ar1, Br1, , 0)
    }

    float sc = sp1[0] * sp2[0];
    int r0 = cb * 4;
#pragma unroll
    for (int m = 0; m < 8; ++m) {
#pragma unroll
        for (int n = 0; n < 4; ++n) {
            float* p = Cb + (size_t)(m0 + wr * 128 + m * 16 + r0) * N +
                       (n0 + wc * 64 + n * 16 + l15);
#pragma unroll
            for (int r = 0; r < 4; ++r) p[(size_t)r * N] = sc * (float)acc[m][n][r];
        }
    }
#undef ISSUE
#undef HALF
}

extern "C" void kernel_launch(void* const* d_in, const int* in_sizes, int n_in,
                              void* d_out, int out_size, void* d_ws, size_t ws_size,
                              hipStream_t stream) {
    const float* x1 = (const float*)d_in[0];
    const float* x2 = (const float*)d_in[1];
    const float* s1 = (const float*)d_in[2];
    const float* z1 = (const float*)d_in[3];
    const float* s2 = (const float*)d_in[4];
    const float* z2 = (const float*)d_in[5];
    float* out = (float*)d_out;

    const int B = 4, M = 2048, K = 4096, N = 4096;
    const size_t ASZ = (size_t)B * M * K;   // int8 bytes for all of x1
    const size_t BSZ = (size_t)B * K * N;   // int8 bytes for all of x2
    dim3 blk(256);

    static int lds_attr_set = 0;
    if (!lds_attr_set) {
        (void)hipFuncSetAttribute((const void*)gemm_i8,
                                  hipFuncAttributeMaxDynamicSharedMemorySize, 131072);
        lds_attr_set = 1;
    }

    if (ws_size >= ASZ + BSZ) {
        int8_t* Aq = (int8_t*)d_ws;
        int8_t* Bq = Aq + ASZ;
        long n16 = (long)(ASZ / 16);
        quant_lin<<<dim3((unsigned)(n16 / 256)), blk, 0, stream>>>(x1, Aq, s1, z1, n16);
        quant_bt<<<dim3(N / 64, K / 64, B), blk, 0, stream>>>(x2, Bq, s2, z2);
        gemm_i8<<<dim3((M / 256) * (N / 256), 1, B), dim3(512), 131072, stream>>>(
            Aq, Bq, out, s1, s2);
    } else {
        const size_t AB = (size_t)M * K, BB = (size_t)K * N;
        int8_t* Aq = (int8_t*)d_ws;
        int8_t* Bq = Aq + AB;
        for (int b = 0; b < B; ++b) {
            long n16 = (long)(AB / 16);
            quant_lin<<<dim3((unsigned)(n16 / 256)), blk, 0, stream>>>(x1 + (size_t)b * AB, Aq, s1, z1, n16);
            quant_bt<<<dim3(N / 64, K / 64, 1), blk, 0, stream>>>(x2 + (size_t)b * BB, Bq, s2, z2);
            gemm_i8<<<dim3((M / 256) * (N / 256), 1, 1), dim3(512), 131072, stream>>>(
                Aq, Bq, out + (size_t)b * M * N, s1, s2);
        }
    }
}